// Round 11
// baseline (125.836 us; speedup 1.0000x reference)
//
#include <hip/hip_runtime.h>

#define BB  4
#define LL  512
#define HID 256
#define PAi 32
#define OO  64

using bf16x8 = __attribute__((ext_vector_type(8))) short;
using f32x4  = __attribute__((ext_vector_type(4))) float;

__device__ inline ushort f2bf(float x) {
    union { float f; unsigned u; } v; v.f = x;
    unsigned r = (v.u + 0x7fff + ((v.u >> 16) & 1)) >> 16;  // RNE
    return (ushort)r;
}

// Relaxed barrier: order LDS traffic only; global prefetches stay in flight.
// (__syncthreads would emit s_waitcnt vmcnt(0) and drain our c+1/c+2 prefetches.)
__device__ inline void barrier_lds() {
    asm volatile("s_waitcnt lgkmcnt(0)" ::: "memory");
    __builtin_amdgcn_s_barrier();
}

// -------- Kernel 1: h[b,l,p] = dot(hidden[b,l,:], W_in[p,:]) + b_in[p]; f32 + bf16 copies --------
__global__ __launch_bounds__(256) void k_in(const float* __restrict__ hidden,
                                            const float* __restrict__ W_in,
                                            const float* __restrict__ b_in,
                                            float* __restrict__ h,
                                            ushort* __restrict__ hb) {
    __shared__ float4 hid[8 * 64];
    const int tid  = threadIdx.x;
    const int row0 = blockIdx.x * 8;
    const float4* src = (const float4*)(hidden + (size_t)row0 * HID);
    hid[tid]       = src[tid];
    hid[tid + 256] = src[tid + 256];
    __syncthreads();
    const int p = tid & 31;
    const int r = tid >> 5;
    const float4* w = (const float4*)(W_in + (size_t)p * HID);
    float acc = 0.f;
#pragma unroll
    for (int k = 0; k < 64; ++k) {
        float4 hv = hid[r * 64 + k];
        float4 wv = w[k];
        acc += hv.x * wv.x + hv.y * wv.y + hv.z * wv.z + hv.w * wv.w;
    }
    const float val = acc + b_in[p];
    h[(size_t)(row0 + r) * PAi + p]  = val;
    hb[(size_t)(row0 + r) * PAi + p] = f2bf(val);
}

// -------- Kernel 2: t[b,j,o,q] = sum_p h[b,j,p] * W_out[o, p*32+q]  (bf16 out) --------
#define RMID 16
__global__ __launch_bounds__(256) void k_mid(const float* __restrict__ h,
                                             const float* __restrict__ W_out,
                                             ushort* __restrict__ t) {
    __shared__ __attribute__((aligned(16))) float hst[PAi][RMID];
    const int tid  = threadIdx.x;
    const int row0 = blockIdx.x * RMID;
    for (int s = tid; s < RMID * PAi; s += 256) {
        const int r = s >> 5, p = s & 31;
        hst[p][r] = h[(size_t)(row0 + r) * PAi + p];
    }
    __syncthreads();
    const int qg = tid & 7;
    const int o1 = tid >> 3;
    const float4* W4 = (const float4*)W_out;
    float4 accA[RMID], accB[RMID];
#pragma unroll
    for (int r = 0; r < RMID; ++r) {
        accA[r] = float4{0, 0, 0, 0};
        accB[r] = float4{0, 0, 0, 0};
    }
#pragma unroll 2
    for (int p = 0; p < PAi; ++p) {
        const float4 wa = W4[(o1 * PAi + p) * 8 + qg];
        const float4 wb = W4[((o1 + 32) * PAi + p) * 8 + qg];
#pragma unroll
        for (int r4 = 0; r4 < RMID / 4; ++r4) {
            const float4 h4 = *(const float4*)&hst[p][r4 * 4];
            const float hr[4] = {h4.x, h4.y, h4.z, h4.w};
#pragma unroll
            for (int e = 0; e < 4; ++e) {
                const int r = r4 * 4 + e;
                accA[r].x += hr[e] * wa.x; accA[r].y += hr[e] * wa.y;
                accA[r].z += hr[e] * wa.z; accA[r].w += hr[e] * wa.w;
                accB[r].x += hr[e] * wb.x; accB[r].y += hr[e] * wb.y;
                accB[r].z += hr[e] * wb.z; accB[r].w += hr[e] * wb.w;
            }
        }
    }
#pragma unroll
    for (int r = 0; r < RMID; ++r) {
        ushort4 ua, ub;
        ua.x = f2bf(accA[r].x); ua.y = f2bf(accA[r].y); ua.z = f2bf(accA[r].z); ua.w = f2bf(accA[r].w);
        ub.x = f2bf(accB[r].x); ub.y = f2bf(accB[r].y); ub.z = f2bf(accB[r].z); ub.w = f2bf(accB[r].w);
        ushort* dst = t + (size_t)(row0 + r) * OO * PAi;
        *(ushort4*)(dst + (o1 * 8 + qg) * 4)        = ua;
        *(ushort4*)(dst + ((o1 + 32) * 8 + qg) * 4) = ub;
    }
}

// -------- Kernel 3: r10 structure + relaxed (LDS-only) barriers --------
#define SEG  4096
#define CH   256
#define NCH  (SEG / CH)
#define LSTR 260
__global__ __launch_bounds__(256, 2) void k_out(const ushort* __restrict__ t,   // bf16 [B][L*OO][PAi]
                                                const ushort* __restrict__ hb,  // bf16 [B][L][PAi]
                                                const float* __restrict__ pw,
                                                const float* __restrict__ b_out,
                                                float* __restrict__ out) {
    __shared__ float sA[16 * LSTR];  // 16.6 KB each
    __shared__ float sB[16 * LSTR];
    const int tid  = threadIdx.x;
    const int lane = tid & 63;
    const int wave = tid >> 6;
    const int b    = blockIdx.z;
    const int i0   = blockIdx.y * 32;
    const int seg0 = blockIdx.x * SEG;
    const int l15  = lane & 15;
    const int g    = lane >> 4;

    const bf16x8 hf0 = *(const bf16x8*)(hb + ((size_t)(b * LL + i0 + l15)) * PAi + g * 8);
    const bf16x8 hf1 = *(const bf16x8*)(hb + ((size_t)(b * LL + i0 + 16 + l15)) * PAi + g * 8);
    const f32x4 bo4 = *(const f32x4*)(b_out + ((lane * 4) & 63));
    const size_t outrow0 = ((size_t)(b * LL + i0)) * (LL * OO);

    auto loadT = [&](int c, bf16x8* tf) {
        const ushort* tb0 = t + ((size_t)b * LL * OO + seg0 + c * CH + wave * 64 + l15) * PAi + g * 8;
#pragma unroll
        for (int tt = 0; tt < 4; ++tt)
            tf[tt] = *(const bf16x8*)(tb0 + (size_t)tt * (16 * PAi));
    };
    auto loadP = [&](int c, f32x4* pv) {   // pv[8]: it*4+rr -> row it*16+wave*4+rr
        const int cbase = seg0 + c * CH;
#pragma unroll
        for (int it = 0; it < 2; ++it)
#pragma unroll
            for (int rr = 0; rr < 4; ++rr)
                pv[it * 4 + rr] = *(const f32x4*)(pw + outrow0 +
                    (size_t)(it * 16 + wave * 4 + rr) * (LL * OO) + cbase + lane * 4);
    };
    auto mfmaS = [&](const bf16x8* tf, const bf16x8 hfi, float* sbuf) {
#pragma unroll
        for (int tt = 0; tt < 4; ++tt) {
            f32x4 z = {0.f, 0.f, 0.f, 0.f};
            f32x4 a = __builtin_amdgcn_mfma_f32_16x16x32_bf16(tf[tt], hfi, z, 0, 0, 0);
            *(f32x4*)&sbuf[l15 * LSTR + wave * 64 + tt * 16 + g * 4] = a;
        }
    };
    auto cons = [&](int c, int it, const f32x4* pv4, const float* sbuf) {
        const int cbase = seg0 + c * CH;
#pragma unroll
        for (int rr = 0; rr < 4; ++rr) {
            const f32x4 a4 = *(const f32x4*)&sbuf[(wave * 4 + rr) * LSTR + lane * 4];
            f32x4 res = a4 + bo4 + pv4[rr];
            __builtin_nontemporal_store(res, (f32x4*)(out + outrow0 +
                (size_t)(it * 16 + wave * 4 + rr) * (LL * OO) + cbase + lane * 4));
        }
    };

    bf16x8 tf0[4], tf1[4];
    f32x4  pv0[8], pv1[8];

    loadT(0, tf0); loadP(0, pv0);

    for (int c = 0; c < NCH; c += 2) {
        // ---- chunk c (tf0/pv0) ----
        loadT(c + 1, tf1); loadP(c + 1, pv1);     // c+1 < NCH always (NCH even)
        mfmaS(tf0, hf0, sA);
        barrier_lds();
        mfmaS(tf0, hf1, sB);
        cons(c, 0, pv0, sA);
        barrier_lds();
        cons(c, 1, pv0 + 4, sB);
        // ---- chunk c+1 (tf1/pv1) ----
        if (c + 2 < NCH) { loadT(c + 2, tf0); loadP(c + 2, pv0); }
        mfmaS(tf1, hf0, sA);
        barrier_lds();
        mfmaS(tf1, hf1, sB);
        cons(c + 1, 0, pv1, sA);
        barrier_lds();
        cons(c + 1, 1, pv1 + 4, sB);
    }
}

extern "C" void kernel_launch(void* const* d_in, const int* in_sizes, int n_in,
                              void* d_out, int out_size, void* d_ws, size_t ws_size,
                              hipStream_t stream) {
    const float* hidden = (const float*)d_in[0];
    const float* pw     = (const float*)d_in[1];
    const float* W_in   = (const float*)d_in[2];
    const float* b_in   = (const float*)d_in[3];
    const float* W_out  = (const float*)d_in[4];
    const float* b_out  = (const float*)d_in[5];
    float* out = (float*)d_out;

    float*  h  = (float*)d_ws;                                // 65536 f32  (256 KB)
    ushort* hb = (ushort*)(h + (size_t)BB * LL * PAi);        // 65536 bf16 (128 KB)
    ushort* tb = hb + (size_t)BB * LL * PAi;                  // 4194304 bf16 (8 MB)

    k_in <<<dim3(BB * LL / 8), 256, 0, stream>>>(hidden, W_in, b_in, h, hb);
    k_mid<<<dim3(BB * LL / RMID), 256, 0, stream>>>(h, W_out, tb);
    // 8 jo-segments x 16 i-tiles(32) x B = 512 blocks = 2/CU
    k_out<<<dim3(LL * OO / SEG, LL / 32, BB), 256, 0, stream>>>(tb, hb, pw, b_out, out);
}

// Round 12
// 113.363 us; speedup vs baseline: 1.1100x; 1.1100x over previous
//
#include <hip/hip_runtime.h>

#define BB  4
#define LL  512
#define HID 256
#define PAi 32
#define OO  64

using bf16x8 = __attribute__((ext_vector_type(8))) short;
using f32x4  = __attribute__((ext_vector_type(4))) float;

__device__ inline ushort f2bf(float x) {
    union { float f; unsigned u; } v; v.f = x;
    unsigned r = (v.u + 0x7fff + ((v.u >> 16) & 1)) >> 16;  // RNE
    return (ushort)r;
}

// Relaxed barrier: order LDS traffic only; global prefetches stay in flight.
__device__ inline void barrier_lds() {
    asm volatile("s_waitcnt lgkmcnt(0)" ::: "memory");
    __builtin_amdgcn_s_barrier();
}

// -------- Kernel 1: h[b,l,p] = dot(hidden[b,l,:], W_in[p,:]) + b_in[p]; f32 + bf16 copies --------
__global__ __launch_bounds__(256) void k_in(const float* __restrict__ hidden,
                                            const float* __restrict__ W_in,
                                            const float* __restrict__ b_in,
                                            float* __restrict__ h,
                                            ushort* __restrict__ hb) {
    __shared__ float4 hid[8 * 64];
    const int tid  = threadIdx.x;
    const int row0 = blockIdx.x * 8;
    const float4* src = (const float4*)(hidden + (size_t)row0 * HID);
    hid[tid]       = src[tid];
    hid[tid + 256] = src[tid + 256];
    __syncthreads();
    const int p = tid & 31;
    const int r = tid >> 5;
    const float4* w = (const float4*)(W_in + (size_t)p * HID);
    float acc = 0.f;
#pragma unroll
    for (int k = 0; k < 64; ++k) {
        float4 hv = hid[r * 64 + k];
        float4 wv = w[k];
        acc += hv.x * wv.x + hv.y * wv.y + hv.z * wv.z + hv.w * wv.w;
    }
    const float val = acc + b_in[p];
    h[(size_t)(row0 + r) * PAi + p]  = val;
    hb[(size_t)(row0 + r) * PAi + p] = f2bf(val);
}

// -------- Kernel 2: t[b,j,o,q] = sum_p h[b,j,p] * W_out[o, p*32+q]  (bf16 out) --------
#define RMID 16
__global__ __launch_bounds__(256) void k_mid(const float* __restrict__ h,
                                             const float* __restrict__ W_out,
                                             ushort* __restrict__ t) {
    __shared__ __attribute__((aligned(16))) float hst[PAi][RMID];
    const int tid  = threadIdx.x;
    const int row0 = blockIdx.x * RMID;
    for (int s = tid; s < RMID * PAi; s += 256) {
        const int r = s >> 5, p = s & 31;
        hst[p][r] = h[(size_t)(row0 + r) * PAi + p];
    }
    __syncthreads();
    const int qg = tid & 7;
    const int o1 = tid >> 3;
    const float4* W4 = (const float4*)W_out;
    float4 accA[RMID], accB[RMID];
#pragma unroll
    for (int r = 0; r < RMID; ++r) {
        accA[r] = float4{0, 0, 0, 0};
        accB[r] = float4{0, 0, 0, 0};
    }
#pragma unroll 2
    for (int p = 0; p < PAi; ++p) {
        const float4 wa = W4[(o1 * PAi + p) * 8 + qg];
        const float4 wb = W4[((o1 + 32) * PAi + p) * 8 + qg];
#pragma unroll
        for (int r4 = 0; r4 < RMID / 4; ++r4) {
            const float4 h4 = *(const float4*)&hst[p][r4 * 4];
            const float hr[4] = {h4.x, h4.y, h4.z, h4.w};
#pragma unroll
            for (int e = 0; e < 4; ++e) {
                const int r = r4 * 4 + e;
                accA[r].x += hr[e] * wa.x; accA[r].y += hr[e] * wa.y;
                accA[r].z += hr[e] * wa.z; accA[r].w += hr[e] * wa.w;
                accB[r].x += hr[e] * wb.x; accB[r].y += hr[e] * wb.y;
                accB[r].z += hr[e] * wb.z; accB[r].w += hr[e] * wb.w;
            }
        }
    }
#pragma unroll
    for (int r = 0; r < RMID; ++r) {
        ushort4 ua, ub;
        ua.x = f2bf(accA[r].x); ua.y = f2bf(accA[r].y); ua.z = f2bf(accA[r].z); ua.w = f2bf(accA[r].w);
        ub.x = f2bf(accB[r].x); ub.y = f2bf(accB[r].y); ub.z = f2bf(accB[r].z); ub.w = f2bf(accB[r].w);
        ushort* dst = t + (size_t)(row0 + r) * OO * PAi;
        *(ushort4*)(dst + (o1 * 8 + qg) * 4)        = ua;
        *(ushort4*)(dst + ((o1 + 32) * 8 + qg) * 4) = ub;
    }
}

// -------- Kernel 3: block owns a 256-wide jo strip; t loaded ONCE; sweep all 512 i-rows --------
// Per band (16 i-rows): mfma(next band) -> other LDS buffer; consume current band
// (LDS rows + pw + bias -> 1KB-coalesced NT store); refill h/pw regs for band+2; 1 barrier.
// t vector traffic: 128 MB -> 8 MB vs r10. Stream shape identical to r10.
#define WJO  256
#define NIT  (LL / 16)   // 32 bands
#define LSTR 260
__global__ __launch_bounds__(256, 2) void k_out(const ushort* __restrict__ t,   // bf16 [B][L*OO][PAi]
                                                const ushort* __restrict__ hb,  // bf16 [B][L][PAi]
                                                const float* __restrict__ pw,
                                                const float* __restrict__ b_out,
                                                float* __restrict__ out) {
    __shared__ float sA[16 * LSTR];  // 16.6 KB each
    __shared__ float sB[16 * LSTR];
    const int tid  = threadIdx.x;
    const int lane = tid & 63;
    const int wave = tid >> 6;
    const int b    = blockIdx.y;
    const int jo0  = blockIdx.x * WJO;
    const int l15  = lane & 15;
    const int g    = lane >> 4;

    // t fragments for this strip: loaded once, reused by all 32 bands
    bf16x8 tf[4];
    {
        const ushort* tb0 = t + ((size_t)b * LL * OO + jo0 + wave * 64 + l15) * PAi + g * 8;
#pragma unroll
        for (int tt = 0; tt < 4; ++tt)
            tf[tt] = *(const bf16x8*)(tb0 + (size_t)tt * (16 * PAi));
    }
    const f32x4 bo4 = *(const f32x4*)(b_out + ((lane * 4) & 63));

    auto loadH = [&](int it) -> bf16x8 {
        return *(const bf16x8*)(hb + ((size_t)(b * LL + it * 16 + l15)) * PAi + g * 8);
    };
    auto loadP = [&](int it, f32x4* pv) {
#pragma unroll
        for (int rr = 0; rr < 4; ++rr)
            pv[rr] = *(const f32x4*)(pw + ((size_t)(b * LL + it * 16 + wave * 4 + rr)) * (LL * OO)
                                       + jo0 + lane * 4);
    };
    auto mfmaS = [&](const bf16x8 hfi, float* sbuf) {
#pragma unroll
        for (int tt = 0; tt < 4; ++tt) {
            f32x4 z = {0.f, 0.f, 0.f, 0.f};
            f32x4 a = __builtin_amdgcn_mfma_f32_16x16x32_bf16(tf[tt], hfi, z, 0, 0, 0);
            *(f32x4*)&sbuf[l15 * LSTR + wave * 64 + tt * 16 + g * 4] = a;
        }
    };
    auto cons = [&](int it, const f32x4* pv, const float* sbuf) {
#pragma unroll
        for (int rr = 0; rr < 4; ++rr) {
            const f32x4 a4 = *(const f32x4*)&sbuf[(wave * 4 + rr) * LSTR + lane * 4];
            f32x4 res = a4 + bo4 + pv[rr];
            __builtin_nontemporal_store(res,
                (f32x4*)(out + ((size_t)(b * LL + it * 16 + wave * 4 + rr)) * (LL * OO)
                             + jo0 + lane * 4));
        }
    };

    bf16x8 hfA = loadH(0), hfB = loadH(1);
    f32x4  pvA[4], pvB[4];
    loadP(0, pvA); loadP(1, pvB);

    mfmaS(hfA, sA);          // band 0 -> sA
    barrier_lds();

    for (int k = 0; k < NIT; k += 2) {
        // even step k: mfma band k+1 -> sB; consume band k from sA; refill set A <- k+2
        mfmaS(hfB, sB);
        cons(k, pvA, sA);
        if (k + 2 < NIT) { hfA = loadH(k + 2); loadP(k + 2, pvA); }
        barrier_lds();
        // odd step k+1: mfma band k+2 -> sA; consume band k+1 from sB; refill set B <- k+3
        if (k + 2 < NIT) mfmaS(hfA, sA);
        cons(k + 1, pvB, sB);
        if (k + 3 < NIT) { hfB = loadH(k + 3); loadP(k + 3, pvB); }
        barrier_lds();
    }
}

extern "C" void kernel_launch(void* const* d_in, const int* in_sizes, int n_in,
                              void* d_out, int out_size, void* d_ws, size_t ws_size,
                              hipStream_t stream) {
    const float* hidden = (const float*)d_in[0];
    const float* pw     = (const float*)d_in[1];
    const float* W_in   = (const float*)d_in[2];
    const float* b_in   = (const float*)d_in[3];
    const float* W_out  = (const float*)d_in[4];
    const float* b_out  = (const float*)d_in[5];
    float* out = (float*)d_out;

    float*  h  = (float*)d_ws;                                // 65536 f32  (256 KB)
    ushort* hb = (ushort*)(h + (size_t)BB * LL * PAi);        // 65536 bf16 (128 KB)
    ushort* tb = hb + (size_t)BB * LL * PAi;                  // 4194304 bf16 (8 MB)

    k_in <<<dim3(BB * LL / 8), 256, 0, stream>>>(hidden, W_in, b_in, h, hb);
    k_mid<<<dim3(BB * LL / RMID), 256, 0, stream>>>(h, W_out, tb);
    // 128 jo-strips x 4 b = 512 blocks = 2/CU
    k_out<<<dim3(LL * OO / WJO, BB), 256, 0, stream>>>(tb, hb, pw, b_out, out);
}

// Round 13
// 112.150 us; speedup vs baseline: 1.1220x; 1.0108x over previous
//
#include <hip/hip_runtime.h>

#define BB  4
#define LL  512
#define HID 256
#define PAi 32
#define OO  64

using bf16x8 = __attribute__((ext_vector_type(8))) short;
using f32x4  = __attribute__((ext_vector_type(4))) float;

__device__ inline ushort f2bf(float x) {
    union { float f; unsigned u; } v; v.f = x;
    unsigned r = (v.u + 0x7fff + ((v.u >> 16) & 1)) >> 16;  // RNE
    return (ushort)r;
}

// Relaxed barrier: order LDS traffic only; global prefetches stay in flight.
__device__ inline void barrier_lds() {
    asm volatile("s_waitcnt lgkmcnt(0)" ::: "memory");
    __builtin_amdgcn_s_barrier();
}

// -------- Kernel 1: h[b,l,p] = dot(hidden[b,l,:], W_in[p,:]) + b_in[p]; f32 + bf16 copies --------
__global__ __launch_bounds__(256) void k_in(const float* __restrict__ hidden,
                                            const float* __restrict__ W_in,
                                            const float* __restrict__ b_in,
                                            float* __restrict__ h,
                                            ushort* __restrict__ hb) {
    __shared__ float4 hid[8 * 64];
    const int tid  = threadIdx.x;
    const int row0 = blockIdx.x * 8;
    const float4* src = (const float4*)(hidden + (size_t)row0 * HID);
    hid[tid]       = src[tid];
    hid[tid + 256] = src[tid + 256];
    __syncthreads();
    const int p = tid & 31;
    const int r = tid >> 5;
    const float4* w = (const float4*)(W_in + (size_t)p * HID);
    float acc = 0.f;
#pragma unroll
    for (int k = 0; k < 64; ++k) {
        float4 hv = hid[r * 64 + k];
        float4 wv = w[k];
        acc += hv.x * wv.x + hv.y * wv.y + hv.z * wv.z + hv.w * wv.w;
    }
    const float val = acc + b_in[p];
    h[(size_t)(row0 + r) * PAi + p]  = val;
    hb[(size_t)(row0 + r) * PAi + p] = f2bf(val);
}

// -------- Kernel 2: t[b,j,o,q] = sum_p h[b,j,p] * W_out[o, p*32+q]  (bf16 out) --------
#define RMID 16
__global__ __launch_bounds__(256) void k_mid(const float* __restrict__ h,
                                             const float* __restrict__ W_out,
                                             ushort* __restrict__ t) {
    __shared__ __attribute__((aligned(16))) float hst[PAi][RMID];
    const int tid  = threadIdx.x;
    const int row0 = blockIdx.x * RMID;
    for (int s = tid; s < RMID * PAi; s += 256) {
        const int r = s >> 5, p = s & 31;
        hst[p][r] = h[(size_t)(row0 + r) * PAi + p];
    }
    __syncthreads();
    const int qg = tid & 7;
    const int o1 = tid >> 3;
    const float4* W4 = (const float4*)W_out;
    float4 accA[RMID], accB[RMID];
#pragma unroll
    for (int r = 0; r < RMID; ++r) {
        accA[r] = float4{0, 0, 0, 0};
        accB[r] = float4{0, 0, 0, 0};
    }
#pragma unroll 2
    for (int p = 0; p < PAi; ++p) {
        const float4 wa = W4[(o1 * PAi + p) * 8 + qg];
        const float4 wb = W4[((o1 + 32) * PAi + p) * 8 + qg];
#pragma unroll
        for (int r4 = 0; r4 < RMID / 4; ++r4) {
            const float4 h4 = *(const float4*)&hst[p][r4 * 4];
            const float hr[4] = {h4.x, h4.y, h4.z, h4.w};
#pragma unroll
            for (int e = 0; e < 4; ++e) {
                const int r = r4 * 4 + e;
                accA[r].x += hr[e] * wa.x; accA[r].y += hr[e] * wa.y;
                accA[r].z += hr[e] * wa.z; accA[r].w += hr[e] * wa.w;
                accB[r].x += hr[e] * wb.x; accB[r].y += hr[e] * wb.y;
                accB[r].z += hr[e] * wb.z; accB[r].w += hr[e] * wb.w;
            }
        }
    }
#pragma unroll
    for (int r = 0; r < RMID; ++r) {
        ushort4 ua, ub;
        ua.x = f2bf(accA[r].x); ua.y = f2bf(accA[r].y); ua.z = f2bf(accA[r].z); ua.w = f2bf(accA[r].w);
        ub.x = f2bf(accB[r].x); ub.y = f2bf(accB[r].y); ub.z = f2bf(accB[r].z); ub.w = f2bf(accB[r].w);
        ushort* dst = t + (size_t)(row0 + r) * OO * PAi;
        *(ushort4*)(dst + (o1 * 8 + qg) * 4)        = ua;
        *(ushort4*)(dst + ((o1 + 32) * 8 + qg) * 4) = ub;
    }
}

// -------- Kernel 3: 256-wide jo strip per block; t loaded once; 256-i-row half-sweep --------
// r12 structure with the i-sweep split across 2 blocks (blockIdx.y) -> 1024 blocks = 4/CU,
// restoring r7's memory-level parallelism at r12's reduced traffic.
#define WJO  256
#define NIT2 (LL / 32)   // 16 bands of 16 rows per half-sweep
#define LSTR 260
__global__ __launch_bounds__(256, 4) void k_out(const ushort* __restrict__ t,   // bf16 [B][L*OO][PAi]
                                                const ushort* __restrict__ hb,  // bf16 [B][L][PAi]
                                                const float* __restrict__ pw,
                                                const float* __restrict__ b_out,
                                                float* __restrict__ out) {
    __shared__ float sA[16 * LSTR];  // 16.6 KB each
    __shared__ float sB[16 * LSTR];
    const int tid   = threadIdx.x;
    const int lane  = tid & 63;
    const int wave  = tid >> 6;
    const int b     = blockIdx.z;
    const int ibase = blockIdx.y * (LL / 2);
    const int jo0   = blockIdx.x * WJO;
    const int l15   = lane & 15;
    const int g     = lane >> 4;

    // t fragments for this strip: loaded once, reused by all bands
    bf16x8 tf[4];
    {
        const ushort* tb0 = t + ((size_t)b * LL * OO + jo0 + wave * 64 + l15) * PAi + g * 8;
#pragma unroll
        for (int tt = 0; tt < 4; ++tt)
            tf[tt] = *(const bf16x8*)(tb0 + (size_t)tt * (16 * PAi));
    }
    const f32x4 bo4 = *(const f32x4*)(b_out + ((lane * 4) & 63));

    auto loadH = [&](int it) -> bf16x8 {
        return *(const bf16x8*)(hb + ((size_t)(b * LL + ibase + it * 16 + l15)) * PAi + g * 8);
    };
    auto loadP = [&](int it, f32x4* pv) {
#pragma unroll
        for (int rr = 0; rr < 4; ++rr)
            pv[rr] = *(const f32x4*)(pw + ((size_t)(b * LL + ibase + it * 16 + wave * 4 + rr)) * (LL * OO)
                                       + jo0 + lane * 4);
    };
    auto mfmaS = [&](const bf16x8 hfi, float* sbuf) {
#pragma unroll
        for (int tt = 0; tt < 4; ++tt) {
            f32x4 z = {0.f, 0.f, 0.f, 0.f};
            f32x4 a = __builtin_amdgcn_mfma_f32_16x16x32_bf16(tf[tt], hfi, z, 0, 0, 0);
            *(f32x4*)&sbuf[l15 * LSTR + wave * 64 + tt * 16 + g * 4] = a;
        }
    };
    auto cons = [&](int it, const f32x4* pv, const float* sbuf) {
#pragma unroll
        for (int rr = 0; rr < 4; ++rr) {
            const f32x4 a4 = *(const f32x4*)&sbuf[(wave * 4 + rr) * LSTR + lane * 4];
            f32x4 res = a4 + bo4 + pv[rr];
            __builtin_nontemporal_store(res,
                (f32x4*)(out + ((size_t)(b * LL + ibase + it * 16 + wave * 4 + rr)) * (LL * OO)
                             + jo0 + lane * 4));
        }
    };

    bf16x8 hfA = loadH(0), hfB = loadH(1);
    f32x4  pvA[4], pvB[4];
    loadP(0, pvA); loadP(1, pvB);

    mfmaS(hfA, sA);          // band 0 -> sA
    barrier_lds();

    for (int k = 0; k < NIT2; k += 2) {
        // even step k: mfma band k+1 -> sB; consume band k from sA; refill set A <- k+2
        mfmaS(hfB, sB);
        cons(k, pvA, sA);
        if (k + 2 < NIT2) { hfA = loadH(k + 2); loadP(k + 2, pvA); }
        barrier_lds();
        // odd step k+1: mfma band k+2 -> sA; consume band k+1 from sB; refill set B <- k+3
        if (k + 2 < NIT2) mfmaS(hfA, sA);
        cons(k + 1, pvB, sB);
        if (k + 3 < NIT2) { hfB = loadH(k + 3); loadP(k + 3, pvB); }
        barrier_lds();
    }
}

extern "C" void kernel_launch(void* const* d_in, const int* in_sizes, int n_in,
                              void* d_out, int out_size, void* d_ws, size_t ws_size,
                              hipStream_t stream) {
    const float* hidden = (const float*)d_in[0];
    const float* pw     = (const float*)d_in[1];
    const float* W_in   = (const float*)d_in[2];
    const float* b_in   = (const float*)d_in[3];
    const float* W_out  = (const float*)d_in[4];
    const float* b_out  = (const float*)d_in[5];
    float* out = (float*)d_out;

    float*  h  = (float*)d_ws;                                // 65536 f32  (256 KB)
    ushort* hb = (ushort*)(h + (size_t)BB * LL * PAi);        // 65536 bf16 (128 KB)
    ushort* tb = hb + (size_t)BB * LL * PAi;                  // 4194304 bf16 (8 MB)

    k_in <<<dim3(BB * LL / 8), 256, 0, stream>>>(hidden, W_in, b_in, h, hb);
    k_mid<<<dim3(BB * LL / RMID), 256, 0, stream>>>(h, W_out, tb);
    // 128 jo-strips x 2 i-halves x 4 b = 1024 blocks = 4/CU
    k_out<<<dim3(LL * OO / WJO, 2, BB), 256, 0, stream>>>(tb, hb, pw, b_out, out);
}